// Round 1
// baseline (76.046 us; speedup 1.0000x reference)
//
#include <hip/hip_runtime.h>
#include <cstdint>

// ---------------------------------------------------------------------------
// JAX PRNG replication (verified bit-exact in round 1, absmax 0.0).
// key(42) -> threefry2x32 key (0,42), jax_threefry_partitionable semantics.
// ---------------------------------------------------------------------------
__host__ __device__ inline void threefry2x32(uint32_t k0, uint32_t k1,
                                             uint32_t x0, uint32_t x1,
                                             uint32_t& o0, uint32_t& o1) {
  const uint32_t ks2 = k0 ^ k1 ^ 0x1BD11BDAu;
  uint32_t v0 = x0 + k0, v1 = x1 + k1;
#define RL(v, r) (((v) << (r)) | ((v) >> (32 - (r))))
#define RND4(a, b, c, d)                                                       \
  v0 += v1; v1 = RL(v1, a); v1 ^= v0;                                          \
  v0 += v1; v1 = RL(v1, b); v1 ^= v0;                                          \
  v0 += v1; v1 = RL(v1, c); v1 ^= v0;                                          \
  v0 += v1; v1 = RL(v1, d); v1 ^= v0;
  RND4(13, 15, 26, 6)  v0 += k1;  v1 += ks2 + 1u;
  RND4(17, 29, 16, 24) v0 += ks2; v1 += k0 + 2u;
  RND4(13, 15, 26, 6)  v0 += k0;  v1 += k1 + 3u;
  RND4(17, 29, 16, 24) v0 += k1;  v1 += ks2 + 4u;
  RND4(13, 15, 26, 6)  v0 += ks2; v1 += k0 + 5u;
#undef RND4
#undef RL
  o0 = v0; o1 = v1;
}

#define IN_F 512
#define OUT_F 512
#define BATCH 512

// ---------------------------------------------------------------------------
// K1: mask generation — UNCHANGED (bit-exact verified, absmax 0.0).
// M[o][i] = selected ? 0 : 1e9.
// ---------------------------------------------------------------------------
__global__ __launch_bounds__(512) void gen_mask_kernel(
    const float* __restrict__ pw, float* __restrict__ M,
    uint32_t kb0, uint32_t kb1, uint32_t kl0, uint32_t kl1) {
  const int o = blockIdx.x;
  const int i = threadIdx.x;

  const float2 w = ((const float2*)pw)[o * IN_F + i];
  const float mx = fmaxf(w.x, w.y);
  const float e0 = expf(w.x - mx);
  const float e1 = expf(w.y - mx);
  const float p = e1 / (e0 + e1);

  const uint32_t n = (uint32_t)(o * IN_F + i);
  uint32_t h0, h1;
  threefry2x32(kb0, kb1, 0u, n, h0, h1);
  const uint32_t bits = h0 ^ h1;
  const float u = __uint_as_float((bits >> 9) | 0x3F800000u) - 1.0f;
  const bool c = u < p;

  __shared__ unsigned long long words[8];
  __shared__ int cnt;
  if (i == 0) cnt = 0;
  __syncthreads();
  const unsigned long long bal = __ballot(c);
  if ((i & 63) == 0) {
    words[i >> 6] = bal;
    atomicAdd(&cnt, __popcll(bal));
  }
  __syncthreads();
  if (cnt == 0 && i == 0) {
    uint32_t c0, c1;
    threefry2x32(kl0, kl1, 0u, (uint32_t)o, c0, c1);
    const uint32_t rb = c0 ^ c1;
    const uint32_t col = rb & (IN_F - 1);
    words[col >> 6] |= (1ull << (col & 63u));
  }
  __syncthreads();
  const bool sel = (words[i >> 6] >> (i & 63)) & 1ull;
  M[o * IN_F + i] = sel ? 0.0f : 1e9f;
}

// ---------------------------------------------------------------------------
// K2 v2: min-plus, lane = o.
//  - M tile [64 o][128 k] staged straight from M's row-major layout via
//    global_load_lds width=16 (no transpose). Read as ds_read_b128 (4 k's per
//    instr). Stride-512B row reads would be a 32-way bank conflict; fixed with
//    XOR swizzle byte ^= (row&7)<<4 applied on the GLOBAL source address
//    (LDS dest must stay linear for global_load_lds) and on the read address.
//    Each consecutive 8-lane group then covers all 8 distinct 16B bank slots.
//  - x[b][k] is wave-uniform (b from readfirstlane(wave id), k = loop var)
//    -> compiler emits s_load_dwordx4: zero LDS, zero VALU for the x operand.
//  - 256 blocks (1/CU) x 256 threads; block = 64 o x 16 b (4 waves x 4 accs).
//    Per 4k per wave: 1 ds_read_b128 (~12cy/CU-pipe) vs 64cy VALU per SIMD
//    -> VALU-bound at the 2-instr-per-output-k floor (~3.4 us device-wide).
//  - K chunked at 128, double-buffered (64 KB LDS), stage(next) issued before
//    compute(cur) so L2 latency hides under the MFMA-free VALU loop.
// ---------------------------------------------------------------------------
#define OTILE 64
#define KT2 128
#define NB 4  // b's (accumulators) per thread

__global__ __launch_bounds__(256) void minplus2_kernel(
    const float* __restrict__ x, const float* __restrict__ M,
    float* __restrict__ out) {
  __shared__ float ms[2][OTILE * KT2];  // 2 x 32 KB

  const int tid = threadIdx.x;
  const int lane = tid & 63;
  const int w = __builtin_amdgcn_readfirstlane(tid >> 6);  // wave id 0..3
  const int o0 = blockIdx.y * OTILE;
  const int bb = blockIdx.x * (4 * NB) + w * NB;  // first b of this wave

  const int swz = (lane & 7) << 4;  // read-side XOR swizzle (bytes)

  // Stage one 64x128 chunk: wave w covers rows 16w..16w+15, 2 rows per instr.
  // LDS dest is linear (base + lane*16); source address carries the inverse
  // swizzle so that LDS[row][p] == M[row][ (p ^ ((row&7)<<4)) / 4 ].
  auto stage = [&](int c, int s) {
    const int lr = lane >> 5;          // 0/1: which of the 2 rows
    const int q = (lane & 31) << 4;    // byte offset within row (0..496)
#pragma unroll
    for (int j = 0; j < 8; ++j) {
      const int r = w * 16 + 2 * j + lr;  // row within tile (== o_local)
      const float* src = M + (size_t)(o0 + r) * IN_F + c * KT2 +
                         ((q ^ ((r & 7) << 4)) >> 2);
      __builtin_amdgcn_global_load_lds(
          (const __attribute__((address_space(1))) void*)src,
          (__attribute__((address_space(3))) void*)&ms[s][(w * 16 + 2 * j) * KT2],
          16, 0, 0);
    }
  };

  float acc0 = 1e30f, acc1 = 1e30f, acc2 = 1e30f, acc3 = 1e30f;

  stage(0, 0);
  __syncthreads();

  for (int c = 0; c < IN_F / KT2; ++c) {
    if (c + 1 < IN_F / KT2) stage(c + 1, (c + 1) & 1);

    const char* mrow = (const char*)&ms[c & 1][0] + lane * (KT2 * 4);
    const float* xb = x + c * KT2;

#pragma unroll 8
    for (int k4 = 0; k4 < KT2; k4 += 4) {
      const float4 mv = *(const float4*)(mrow + ((k4 * 4) ^ swz));
      {
        const float4 xv = *(const float4*)&xb[(bb + 0) * IN_F + k4];
        acc0 = fminf(acc0, fminf(fminf(xv.x + mv.x, xv.y + mv.y),
                                 fminf(xv.z + mv.z, xv.w + mv.w)));
      }
      {
        const float4 xv = *(const float4*)&xb[(bb + 1) * IN_F + k4];
        acc1 = fminf(acc1, fminf(fminf(xv.x + mv.x, xv.y + mv.y),
                                 fminf(xv.z + mv.z, xv.w + mv.w)));
      }
      {
        const float4 xv = *(const float4*)&xb[(bb + 2) * IN_F + k4];
        acc2 = fminf(acc2, fminf(fminf(xv.x + mv.x, xv.y + mv.y),
                                 fminf(xv.z + mv.z, xv.w + mv.w)));
      }
      {
        const float4 xv = *(const float4*)&xb[(bb + 3) * IN_F + k4];
        acc3 = fminf(acc3, fminf(fminf(xv.x + mv.x, xv.y + mv.y),
                                 fminf(xv.z + mv.z, xv.w + mv.w)));
      }
    }
    __syncthreads();
  }

  out[(size_t)(bb + 0) * OUT_F + o0 + lane] = acc0;
  out[(size_t)(bb + 1) * OUT_F + o0 + lane] = acc1;
  out[(size_t)(bb + 2) * OUT_F + o0 + lane] = acc2;
  out[(size_t)(bb + 3) * OUT_F + o0 + lane] = acc3;
}

extern "C" void kernel_launch(void* const* d_in, const int* in_sizes, int n_in,
                              void* d_out, int out_size, void* d_ws, size_t ws_size,
                              hipStream_t stream) {
  (void)in_sizes; (void)n_in; (void)out_size; (void)ws_size;
  const float* x = (const float*)d_in[0];   // [512, 512]
  const float* pw = (const float*)d_in[1];  // [512, 512, 2]
  float* M = (float*)d_ws;                  // 1 MB
  float* out = (float*)d_out;

  uint32_t kb0, kb1, kf0, kf1, kl0, kl1;
  threefry2x32(0u, 42u, 0u, 0u, kb0, kb1);   // k_bern = hash(key; 0,0)
  threefry2x32(0u, 42u, 0u, 1u, kf0, kf1);   // k_fix  = hash(key; 0,1)
  threefry2x32(kf0, kf1, 0u, 1u, kl0, kl1);  // randint lower-bits key

  gen_mask_kernel<<<dim3(OUT_F), dim3(IN_F), 0, stream>>>(pw, M, kb0, kb1, kl0, kl1);
  minplus2_kernel<<<dim3(BATCH / (4 * NB), OUT_F / OTILE), dim3(256), 0, stream>>>(x, M, out);
}